// Round 12
// baseline (253.406 us; speedup 1.0000x reference)
//
#include <hip/hip_runtime.h>
#include <hip/hip_bf16.h>

// ---------------------------------------------------------------------------
// NHRepNet fused forward, Round 12: two-tile software pipeline per block.
//
// Established (R1-R11): occupancy tiers power-of-2 (64/128/256 regs); at-cap
// budgets spill (watch WRITE_SIZE); A-traffic = 128KB/pts-per-tile; pipe
// demands VALU 57 / LDS 54 / L1A 36 / MFMA 35 us but wall 124us because the
// k-loop phase (LDS+L1+MFMA) and epilogue phase (VALU) are phase-locked by
// block-wide barriers -> additive.
//
// R12: each block processes TWO 48-pt tiles at complementary phases. Every
// region between barriers = kloop(T_a, layer l) source-interleaved with
// epilogue(T_b, layer l-1): independent work, so epi VALU fills the kloop's
// ds_read/MFMA bubbles inside each wave. acc0+acc1 = 48 AGPR + ~55 arch regs
// ~ 103 <= 128-tier (headroom kept, R10 lesson). LDS ~52KB -> 2 blk/CU.
// Schedule:  R0: kloop T0 L0 | R1: kloop T1 L0 + epi T0 L0 |
//   l=1..6: { kloop T0 l + epi T1 l-1 } { kloop T1 l + epi T0 l } |
//   R14: epi T1 L6 | R15: layer7 (waves 0-2 T0, 3-5 T1) + CSG + store.
// ---------------------------------------------------------------------------

using bf16x8 = __attribute__((ext_vector_type(8))) __bf16;
using f32x4  = __attribute__((ext_vector_type(4))) float;

#define LDA 264   // padded activation row stride (bf16), proven conflict-ok

#define OFFW0 0
#define OFFW1 8192
#define OFFW7 401408
#define WSB_BYTE_OFF 811008   // fp32 bias region
#define OFFB7 1792            // L0..L6 at l*256; L7 at 1792 (16 floats, padded)

#define SCALE_T2 144.26950408889634f      // 100*log2(e)
#define INV_SQRT2 0.70710678118654752f
#define LN2_100 0.0069314718055994531f    // ln2/100

__device__ __forceinline__ float fast_exp2(float x) {
#if __has_builtin(__builtin_amdgcn_exp2f)
    return __builtin_amdgcn_exp2f(x);
#else
    return exp2f(x);
#endif
}
__device__ __forceinline__ float fast_log2(float x) {
#if __has_builtin(__builtin_amdgcn_logf)
    return __builtin_amdgcn_logf(x);
#else
    return log2f(x);
#endif
}

// a2 = max(t2,0) + log2(1 + 2^-|t2|)   (t2-domain; scales folded into weights)
__device__ __forceinline__ float softplus_t2(float t2) {
    float e = fast_exp2(-fabsf(t2));
    float l = fast_log2(1.0f + e);
    return fmaxf(t2, 0.0f) + l;
}

__device__ __forceinline__ unsigned short bf16_rne(float f) {
    unsigned int u = __float_as_uint(f);
    unsigned int r = u + 0x7FFFu + ((u >> 16) & 1u);
    return (unsigned short)(r >> 16);
}

// One epilogue chunk: channels strip i, point-column nt of a consumed acc.
// Writes 4 activated bf16 values for 16 points into dst (in-place buffer).
__device__ __forceinline__ void epi_chunk(
    f32x4 (&acc)[2][3], int i, int nt,
    unsigned short* dst, const float* xst, bool splice,
    int wave, int lane)
{
    const int quad = lane >> 4;
    const int l15  = lane & 15;
    const int chb  = (wave * 2 + i) * 16 + quad * 4;
    const int pt   = nt * 16 + l15;
    float vv[4];
#pragma unroll
    for (int r = 0; r < 4; ++r) {
        float s = softplus_t2(acc[i][nt][r]);
        if (splice) {
            const int ch = chb + r;
            if (ch >= 253)  // layer-3 skip: raw x (W4 rows absorb scales)
                s = xst[pt * 4 + (ch - 253)];
        }
        vv[r] = s;
    }
    __hip_bfloat162 p01 = __float22bfloat162_rn(float2{vv[0], vv[1]});
    __hip_bfloat162 p23 = __float22bfloat162_rn(float2{vv[2], vv[3]});
    uint2 pk;
    pk.x = *(unsigned int*)&p01;
    pk.y = *(unsigned int*)&p23;
    *(uint2*)(dst + pt * LDA + chb) = pk;
}

// Region: k-loop of tile A (layer weights wfragA/biasA, source actA -> accA)
// interleaved with epilogue of tile B (consume accB -> write actB).
template <int KK, bool EPI>
__device__ __forceinline__ void region(
    const unsigned short* __restrict__ wfragA, const float* __restrict__ biasA,
    const unsigned short* __restrict__ actA, f32x4 (&accA)[2][3],
    unsigned short* actB, const float* xstB, f32x4 (&accB)[2][3], bool spliceB,
    int wave, int lane)
{
    const int quad = lane >> 4;
    const int l15  = lane & 15;

#pragma unroll
    for (int i = 0; i < 2; ++i) {
        const int chb = (wave * 2 + i) * 16 + quad * 4;
        const float4 b4 = *(const float4*)(biasA + chb);
#pragma unroll
        for (int nt = 0; nt < 3; ++nt)
            accA[i][nt] = f32x4{b4.x, b4.y, b4.z, b4.w};
    }

    const unsigned short* wbase = wfragA + (wave * 2 * KK * 64 + lane) * 8;

#pragma unroll
    for (int kk = 0; kk < KK; ++kk) {
        bf16x8 bfr[3];
#pragma unroll
        for (int nt = 0; nt < 3; ++nt)
            bfr[nt] = *(const bf16x8*)(actA + (nt * 16 + l15) * LDA + kk * 32 + quad * 8);
#pragma unroll
        for (int i = 0; i < 2; ++i) {
            bf16x8 afr = *(const bf16x8*)(wbase + (i * KK + kk) * 512);
#pragma unroll
            for (int nt = 0; nt < 3; ++nt)
                accA[i][nt] = __builtin_amdgcn_mfma_f32_16x16x32_bf16(afr, bfr[nt], accA[i][nt], 0, 0, 0);
        }
        if (EPI && kk < 6)   // interleave one epi chunk per kk-step
            epi_chunk(accB, kk & 1, kk >> 1, actB, xstB, spliceB, wave, lane);
    }
    if (EPI && KK == 1) {    // layer-0 region: run remaining chunks
#pragma unroll
        for (int c = 1; c < 6; ++c)
            epi_chunk(accB, c & 1, c >> 1, actB, xstB, spliceB, wave, lane);
    }
}

// Epilogue-only region (pipeline drain).
__device__ __forceinline__ void epi_all(
    f32x4 (&acc)[2][3], unsigned short* dst, const float* xst, bool splice,
    int wave, int lane)
{
#pragma unroll
    for (int c = 0; c < 6; ++c)
        epi_chunk(acc, c & 1, c >> 1, dst, xst, splice, wave, lane);
}

__global__ __launch_bounds__(512, 4)
void nhrep_main(const float* __restrict__ x, float* __restrict__ out,
                const unsigned short* __restrict__ wsW,
                const float* __restrict__ wsB, int npts)
{
    __shared__ unsigned short actT0[48 * LDA];  // 25344 B
    __shared__ unsigned short actT1[48 * LDA];  // 25344 B
    __shared__ float xst[96 * 4];               // 1536 B -> 52224 B (2 blk/CU)
    const int tid  = threadIdx.x;
    const int wave = tid >> 6, lane = tid & 63;
    const int quad = lane >> 4, l15 = lane & 15;
    const int base_pt = blockIdx.x * 96;

    // stage both tiles: channels 0..2 real, zero-pad to 32 (K-pad for layer 0)
    for (int i = tid; i < 96 * 32; i += 512) {
        const int pt = i >> 5, ch = i & 31;
        const int ptg = base_pt + pt;
        float v = 0.0f;
        if (ch < 3 && ptg < npts) v = x[ptg * 3 + ch];
        unsigned short* dst = (pt < 48) ? (actT0 + pt * LDA + ch)
                                        : (actT1 + (pt - 48) * LDA + ch);
        *dst = bf16_rne(v);
        if (ch < 4) xst[pt * 4 + ch] = (ch < 3) ? v : 0.0f;
    }
    __syncthreads();

    f32x4 acc0[2][3], acc1[2][3];
    const float* xst0 = xst;
    const float* xst1 = xst + 48 * 4;

    // R0: kloop T0 L0 (prologue, no epi partner yet)
    region<1, false>(wsW + OFFW0, wsB, actT0, acc0,
                     actT1, xst1, acc1, false, wave, lane);
    __syncthreads();
    // R1: kloop T1 L0 + epi T0 L0
    region<1, true>(wsW + OFFW0, wsB, actT1, acc1,
                    actT0, xst0, acc0, false, wave, lane);
    __syncthreads();

#pragma unroll 1
    for (int l = 1; l <= 6; ++l) {
        const unsigned short* wl = wsW + OFFW1 + (l - 1) * 65536;
        const float* bl = wsB + l * 256;
        // kloop T0 layer l + epi T1 layer l-1
        region<8, true>(wl, bl, actT0, acc0,
                        actT1, xst1, acc1, (l - 1) == 3, wave, lane);
        __syncthreads();
        // kloop T1 layer l + epi T0 layer l
        region<8, true>(wl, bl, actT1, acc1,
                        actT0, xst0, acc0, l == 3, wave, lane);
        __syncthreads();
    }

    // R14: epi T1 L6 (drain)
    epi_all(acc1, actT1, xst1, false, wave, lane);
    __syncthreads();

    // R15: layer 7 (256->8, W7 pre-scaled ln2/100, b7 raw) + CSG + store.
    // Waves 0..2 -> T0 point-groups, waves 3..5 -> T1.
    if (wave < 6) {
        const bool t0 = wave < 3;
        const unsigned short* act = t0 ? actT0 : actT1;
        const int wl = t0 ? wave : wave - 3;
        const int pbase = base_pt + (t0 ? 0 : 48) + wl * 16;

        const float4 b4 = *(const float4*)(wsB + OFFB7 + quad * 4);  // quads>=2: zeros
        f32x4 acc = f32x4{b4.x, b4.y, b4.z, b4.w};
        const unsigned short* w7 = wsW + OFFW7;
#pragma unroll
        for (int kk = 0; kk < 8; ++kk) {
            bf16x8 bfr = *(const bf16x8*)(act + (wl * 16 + l15) * LDA + kk * 32 + quad * 8);
            bf16x8 afr = *(const bf16x8*)(w7 + (kk * 64 + lane) * 8);
            acc = __builtin_amdgcn_mfma_f32_16x16x32_bf16(afr, bfr, acc, 0, 0, 0);
        }
        // quad0 lanes hold ch0-3, quad1 ch4-7 for pt = wl*16+l15
        float u0 = __shfl(acc[0], l15 + 16);
        float u1 = __shfl(acc[1], l15 + 16);
        float u2 = __shfl(acc[2], l15 + 16);
        float u3 = __shfl(acc[3], l15 + 16);
        if (quad == 0) {
            const int ptg = pbase + l15;
            if (ptg < npts) {
                const float v0 = acc[0], v1 = acc[1], v2 = acc[2], v3 = acc[3];
                const float v4 = u0, v5 = u1, v6 = u2, v7 = u3;
                const float m23   = fminf(v2, v3);
                const float m67   = fmaxf(v6, v7);
                const float m4567 = fminf(fminf(v4, v5), m67);
                const float h     = fmaxf(fmaxf(v0, v1), fmaxf(m23, m4567));
                float* o = out + (long)ptg * 9;
                o[0] = h;
                o[1] = v0; o[2] = v1; o[3] = v2; o[4] = v3;
                o[5] = v4; o[6] = v5; o[7] = v6; o[8] = v7;
            }
        }
    }
}

// ---------------------------------------------------------------------------
// Fused prepack with scale folding (proven since R4, identity k-mapping).
// Frag (mt,kk,lane,j) = scale(l,k) * W^T[mt*16+(lane&15)][kk*32+(lane>>4)*8+j]
// ---------------------------------------------------------------------------
struct PackArgs {
    const float* W[8];
    const float* b[8];
};

#define TOTAL_FRAGS 50688
#define TOTAL_BIAS  1808

__global__ void prepack_all(PackArgs args, unsigned short* __restrict__ dstW,
                            float* __restrict__ dstB)
{
    const int t = blockIdx.x * blockDim.x + threadIdx.x;
    const int FB[9]  = {0, 1024, 9216, 17408, 25600, 33792, 41984, 50176, 50688};
    const int KKs[8] = {1, 8, 8, 8, 8, 8, 8, 8};
    const int ind[8] = {3, 256, 256, 256, 256, 256, 256, 256};
    const int outd[8]= {256, 256, 256, 253, 256, 256, 256, 8};

    if (t < TOTAL_FRAGS) {
        int l = 0;
        while (t >= FB[l + 1]) ++l;
        const int f    = t - FB[l];
        const int lane = f & 63;
        const int kk   = (f >> 6) % KKs[l];
        const int mt   = f / (64 * KKs[l]);
        const int o    = mt * 16 + (lane & 15);
        const int kb   = kk * 32 + (lane >> 4) * 8;
        const float* W = args.W[l];
        const int in_d = ind[l], out_d = outd[l];

        unsigned short v[8];
#pragma unroll
        for (int j = 0; j < 8; ++j) {
            const int k = kb + j;
            float w = 0.0f;
            if (k < in_d && o < out_d) {
                float sc = 1.0f;
                if (l == 0) sc = SCALE_T2;
                else if (l == 4) sc = (k < 253) ? INV_SQRT2 : (SCALE_T2 * INV_SQRT2);
                else if (l == 7) sc = LN2_100;
                w = W[k * out_d + o] * sc;
            }
            unsigned int u = __float_as_uint(w);
            v[j] = (unsigned short)((u + 0x7FFFu + ((u >> 16) & 1u)) >> 16);
        }
        uint4 p;
        p.x = (unsigned int)v[0] | ((unsigned int)v[1] << 16);
        p.y = (unsigned int)v[2] | ((unsigned int)v[3] << 16);
        p.z = (unsigned int)v[4] | ((unsigned int)v[5] << 16);
        p.w = (unsigned int)v[6] | ((unsigned int)v[7] << 16);
        *(uint4*)(dstW + (long)t * 8) = p;
    } else if (t < TOTAL_FRAGS + TOTAL_BIAS) {
        const int u = t - TOTAL_FRAGS;
        const int l = (u < 1792) ? (u >> 8) : 7;
        const int idx = (l < 7) ? (u & 255) : (u - 1792);
        const float sc = (l < 7) ? SCALE_T2 : 1.0f;   // b7 stays in output units
        dstB[u] = (idx < outd[l]) ? args.b[l][idx] * sc : 0.0f;
    }
}

extern "C" void kernel_launch(void* const* d_in, const int* in_sizes, int n_in,
                              void* d_out, int out_size, void* d_ws, size_t ws_size,
                              hipStream_t stream)
{
    const float* x = (const float*)d_in[0];
    unsigned short* wsW = (unsigned short*)d_ws;
    float* wsB = (float*)((char*)d_ws + WSB_BYTE_OFF);

    PackArgs pa;
    for (int l = 0; l < 8; ++l) {
        pa.W[l] = (const float*)d_in[1 + 2 * l];
        pa.b[l] = (const float*)d_in[2 + 2 * l];
    }
    const int ptot = TOTAL_FRAGS + TOTAL_BIAS;
    prepack_all<<<(ptot + 255) / 256, 256, 0, stream>>>(pa, wsW, wsB);

    const int npts = in_sizes[0] / 3;            // 100000
    const int nblk = (npts + 95) / 96;           // 1042 two-tile blocks
    nhrep_main<<<nblk, 512, 0, stream>>>(x, (float*)d_out, wsW, wsB, npts);
}

// Round 13
// 219.627 us; speedup vs baseline: 1.1538x; 1.1538x over previous
//
#include <hip/hip_runtime.h>
#include <hip/hip_bf16.h>

// ---------------------------------------------------------------------------
// NHRepNet fused forward, Round 13: quad-domain 256-thr blocks, C=64, nt=3.
//
// Established (R1-R12):
//  - Occupancy tiers: <=64 regs -> 8 w/SIMD, <=128 -> 4, <=256 -> 2.
//  - Simple single-acc structures safe to ~92 regs (R9); dual-acc interleave
//    spills at nominal 112 (R12). Spill gate: WRITE_SIZE >> 4MB.
//  - A(L2) traffic = 128KB/tile_pts/layer; B(LDS) = 512B*(256/C)/pt/layer.
//  - R11 pipes: VALU 57 / LDS 54 / L2A 41 / MFMA 35us, wall 124 -> overlap
//    only 1.5x; block-wide barriers phase-lock waves WITHIN a domain, so
//    more independent domains per CU = more dephasing.
//
// R13: 256-thr blocks (4 waves), wave owns 64 ch (MT=4) x 48 pts (nt=3),
// in-place act, 2 barriers/layer. LDS-B halves (27us), L2A 54us, 4 blocks/CU
// = 4 independent barrier domains, 16 waves/CU at the 128-reg tier.
// acc[4][3]=48 AGPR + ~50 arch ~ 98, headroom ~30.
// ---------------------------------------------------------------------------

using bf16x8 = __attribute__((ext_vector_type(8))) __bf16;
using f32x4  = __attribute__((ext_vector_type(4))) float;

#define LDA 264   // padded activation row stride (bf16)

#define OFFW0 0
#define OFFW1 8192
#define OFFW7 401408
#define WSB_BYTE_OFF 811008   // fp32 bias region
#define OFFB7 1792            // L0..L6 at l*256; L7 at 1792 (16 floats, padded)

#define SCALE_T2 144.26950408889634f      // 100*log2(e)
#define INV_SQRT2 0.70710678118654752f
#define LN2_100 0.0069314718055994531f    // ln2/100

__device__ __forceinline__ float fast_exp2(float x) {
#if __has_builtin(__builtin_amdgcn_exp2f)
    return __builtin_amdgcn_exp2f(x);
#else
    return exp2f(x);
#endif
}
__device__ __forceinline__ float fast_log2(float x) {
#if __has_builtin(__builtin_amdgcn_logf)
    return __builtin_amdgcn_logf(x);
#else
    return log2f(x);
#endif
}

// a2 = max(t2,0) + log2(1 + 2^-|t2|)   (t2-domain; scales folded into weights)
__device__ __forceinline__ float softplus_t2(float t2) {
    float e = fast_exp2(-fabsf(t2));
    float l = fast_log2(1.0f + e);
    return fmaxf(t2, 0.0f) + l;
}

__device__ __forceinline__ unsigned short bf16_rne(float f) {
    unsigned int u = __float_as_uint(f);
    unsigned int r = u + 0x7FFFu + ((u >> 16) & 1u);
    return (unsigned short)(r >> 16);
}

// One 256-out layer, in-place on act[48][LDA]. 4 waves = 4 channel strips
// (wave owns ch [wave*64, wave*64+64)) covering all 48 points (nt=0..2).
// MODE 1 = layer-3 splice (raw x into ch 253..255; W4 rows absorb scales).
template <int KK, int MODE>
__device__ __forceinline__ void layer_mm(
    const unsigned short* __restrict__ wfrag,
    const float* __restrict__ bias,
    unsigned short* act, const float* xst,
    int wave, int lane)
{
    const int quad = lane >> 4;
    const int l15  = lane & 15;

    f32x4 acc[4][3];
#pragma unroll
    for (int i = 0; i < 4; ++i) {
        const int chb = (wave * 4 + i) * 16 + quad * 4;
        const float4 b4 = *(const float4*)(bias + chb);
#pragma unroll
        for (int nt = 0; nt < 3; ++nt)
            acc[i][nt] = f32x4{b4.x, b4.y, b4.z, b4.w};
    }

    const unsigned short* wbase = wfrag + (wave * 4 * KK * 64 + lane) * 8;

#pragma unroll
    for (int kk = 0; kk < KK; ++kk) {
        bf16x8 bfr[3];
#pragma unroll
        for (int nt = 0; nt < 3; ++nt)
            bfr[nt] = *(const bf16x8*)(act + (nt * 16 + l15) * LDA + kk * 32 + quad * 8);
#pragma unroll
        for (int i = 0; i < 4; ++i) {
            bf16x8 afr = *(const bf16x8*)(wbase + (i * KK + kk) * 512);
#pragma unroll
            for (int nt = 0; nt < 3; ++nt)
                acc[i][nt] = __builtin_amdgcn_mfma_f32_16x16x32_bf16(afr, bfr[nt], acc[i][nt], 0, 0, 0);
        }
    }

    __syncthreads();   // all waves done READING act

#pragma unroll
    for (int i = 0; i < 4; ++i) {
        const int chb = (wave * 4 + i) * 16 + quad * 4;
#pragma unroll
        for (int nt = 0; nt < 3; ++nt) {
            const int pt = nt * 16 + l15;
            float vv[4];
#pragma unroll
            for (int r = 0; r < 4; ++r) {
                float s = softplus_t2(acc[i][nt][r]);
                if (MODE == 1) {
                    const int ch = chb + r;
                    if (ch >= 253)  // splice raw x (W4 rows absorb scales)
                        s = xst[pt * 4 + (ch - 253)];
                }
                vv[r] = s;
            }
            __hip_bfloat162 p01 = __float22bfloat162_rn(float2{vv[0], vv[1]});
            __hip_bfloat162 p23 = __float22bfloat162_rn(float2{vv[2], vv[3]});
            uint2 pk;
            pk.x = *(unsigned int*)&p01;
            pk.y = *(unsigned int*)&p23;
            *(uint2*)(act + pt * LDA + chb) = pk;
        }
    }

    __syncthreads();   // writes visible before next layer reads
}

__global__ __launch_bounds__(256, 4)
void nhrep_main(const float* __restrict__ x, float* __restrict__ out,
                const unsigned short* __restrict__ wsW,
                const float* __restrict__ wsB, int npts)
{
    __shared__ unsigned short act[48 * LDA];   // 25344 B
    __shared__ float xst[48 * 4];              // 768 B -> 26112 B (4 blk/CU)
    const int tid  = threadIdx.x;
    const int wave = tid >> 6, lane = tid & 63;
    const int quad = lane >> 4, l15 = lane & 15;
    const int base_pt = blockIdx.x * 48;

    // stage x into act channels 0..2, zero-pad to 32 (K-pad for layer 0)
    for (int i = tid; i < 48 * 32; i += 256) {
        const int pt = i >> 5, ch = i & 31;
        const int ptg = base_pt + pt;
        float v = 0.0f;
        if (ch < 3 && ptg < npts) v = x[ptg * 3 + ch];
        act[pt * LDA + ch] = bf16_rne(v);
        if (ch < 4) xst[pt * 4 + ch] = (ch < 3) ? v : 0.0f;
    }
    __syncthreads();

    layer_mm<1, 0>(wsW + OFFW0, wsB + 0 * 256, act, xst, wave, lane);
    layer_mm<8, 0>(wsW + OFFW1 + 0 * 65536, wsB + 1 * 256, act, xst, wave, lane);
    layer_mm<8, 0>(wsW + OFFW1 + 1 * 65536, wsB + 2 * 256, act, xst, wave, lane);
    layer_mm<8, 1>(wsW + OFFW1 + 2 * 65536, wsB + 3 * 256, act, xst, wave, lane);
    layer_mm<8, 0>(wsW + OFFW1 + 3 * 65536, wsB + 4 * 256, act, xst, wave, lane);
    layer_mm<8, 0>(wsW + OFFW1 + 4 * 65536, wsB + 5 * 256, act, xst, wave, lane);
    layer_mm<8, 0>(wsW + OFFW1 + 5 * 65536, wsB + 6 * 256, act, xst, wave, lane);

    // layer 7: 256 -> 8 (W7 pre-scaled ln2/100, b7 raw). Waves 0..2 handle
    // 16 pts each; act not written again -> no barrier.
    if (wave < 3) {
        const float4 b4 = *(const float4*)(wsB + OFFB7 + quad * 4);  // quads>=2: zeros
        f32x4 acc = f32x4{b4.x, b4.y, b4.z, b4.w};
        const unsigned short* w7 = wsW + OFFW7;
#pragma unroll
        for (int kk = 0; kk < 8; ++kk) {
            bf16x8 bfr = *(const bf16x8*)(act + (wave * 16 + l15) * LDA + kk * 32 + quad * 8);
            bf16x8 afr = *(const bf16x8*)(w7 + (kk * 64 + lane) * 8);
            acc = __builtin_amdgcn_mfma_f32_16x16x32_bf16(afr, bfr, acc, 0, 0, 0);
        }
        // quad0 lanes hold ch0-3, quad1 ch4-7 for pt = wave*16+l15
        float u0 = __shfl(acc[0], l15 + 16);
        float u1 = __shfl(acc[1], l15 + 16);
        float u2 = __shfl(acc[2], l15 + 16);
        float u3 = __shfl(acc[3], l15 + 16);
        if (quad == 0) {
            const int ptg = base_pt + wave * 16 + l15;
            if (ptg < npts) {
                const float v0 = acc[0], v1 = acc[1], v2 = acc[2], v3 = acc[3];
                const float v4 = u0, v5 = u1, v6 = u2, v7 = u3;
                const float m23   = fminf(v2, v3);
                const float m67   = fmaxf(v6, v7);
                const float m4567 = fminf(fminf(v4, v5), m67);
                const float h     = fmaxf(fmaxf(v0, v1), fmaxf(m23, m4567));
                float* o = out + (long)ptg * 9;
                o[0] = h;
                o[1] = v0; o[2] = v1; o[3] = v2; o[4] = v3;
                o[5] = v4; o[6] = v5; o[7] = v6; o[8] = v7;
            }
        }
    }
}

// ---------------------------------------------------------------------------
// Fused prepack with scale folding (proven since R4, identity k-mapping).
// Frag (mt,kk,lane,j) = scale(l,k) * W^T[mt*16+(lane&15)][kk*32+(lane>>4)*8+j]
// ---------------------------------------------------------------------------
struct PackArgs {
    const float* W[8];
    const float* b[8];
};

#define TOTAL_FRAGS 50688
#define TOTAL_BIAS  1808

__global__ void prepack_all(PackArgs args, unsigned short* __restrict__ dstW,
                            float* __restrict__ dstB)
{
    const int t = blockIdx.x * blockDim.x + threadIdx.x;
    const int FB[9]  = {0, 1024, 9216, 17408, 25600, 33792, 41984, 50176, 50688};
    const int KKs[8] = {1, 8, 8, 8, 8, 8, 8, 8};
    const int ind[8] = {3, 256, 256, 256, 256, 256, 256, 256};
    const int outd[8]= {256, 256, 256, 253, 256, 256, 256, 8};

    if (t < TOTAL_FRAGS) {
        int l = 0;
        while (t >= FB[l + 1]) ++l;
        const int f    = t - FB[l];
        const int lane = f & 63;
        const int kk   = (f >> 6) % KKs[l];
        const int mt   = f / (64 * KKs[l]);
        const int o    = mt * 16 + (lane & 15);
        const int kb   = kk * 32 + (lane >> 4) * 8;
        const float* W = args.W[l];
        const int in_d = ind[l], out_d = outd[l];

        unsigned short v[8];
#pragma unroll
        for (int j = 0; j < 8; ++j) {
            const int k = kb + j;
            float w = 0.0f;
            if (k < in_d && o < out_d) {
                float sc = 1.0f;
                if (l == 0) sc = SCALE_T2;
                else if (l == 4) sc = (k < 253) ? INV_SQRT2 : (SCALE_T2 * INV_SQRT2);
                else if (l == 7) sc = LN2_100;
                w = W[k * out_d + o] * sc;
            }
            unsigned int u = __float_as_uint(w);
            v[j] = (unsigned short)((u + 0x7FFFu + ((u >> 16) & 1u)) >> 16);
        }
        uint4 p;
        p.x = (unsigned int)v[0] | ((unsigned int)v[1] << 16);
        p.y = (unsigned int)v[2] | ((unsigned int)v[3] << 16);
        p.z = (unsigned int)v[4] | ((unsigned int)v[5] << 16);
        p.w = (unsigned int)v[6] | ((unsigned int)v[7] << 16);
        *(uint4*)(dstW + (long)t * 8) = p;
    } else if (t < TOTAL_FRAGS + TOTAL_BIAS) {
        const int u = t - TOTAL_FRAGS;
        const int l = (u < 1792) ? (u >> 8) : 7;
        const int idx = (l < 7) ? (u & 255) : (u - 1792);
        const float sc = (l < 7) ? SCALE_T2 : 1.0f;   // b7 stays in output units
        dstB[u] = (idx < outd[l]) ? args.b[l][idx] * sc : 0.0f;
    }
}

extern "C" void kernel_launch(void* const* d_in, const int* in_sizes, int n_in,
                              void* d_out, int out_size, void* d_ws, size_t ws_size,
                              hipStream_t stream)
{
    const float* x = (const float*)d_in[0];
    unsigned short* wsW = (unsigned short*)d_ws;
    float* wsB = (float*)((char*)d_ws + WSB_BYTE_OFF);

    PackArgs pa;
    for (int l = 0; l < 8; ++l) {
        pa.W[l] = (const float*)d_in[1 + 2 * l];
        pa.b[l] = (const float*)d_in[2 + 2 * l];
    }
    const int ptot = TOTAL_FRAGS + TOTAL_BIAS;
    prepack_all<<<(ptot + 255) / 256, 256, 0, stream>>>(pa, wsW, wsB);

    const int npts = in_sizes[0] / 3;            // 100000
    const int nblk = (npts + 47) / 48;           // 2084
    nhrep_main<<<nblk, 256, 0, stream>>>(x, (float*)d_out, wsW, wsB, npts);
}

// Round 14
// 189.067 us; speedup vs baseline: 1.3403x; 1.1616x over previous
//
#include <hip/hip_runtime.h>
#include <hip/hip_bf16.h>

// ---------------------------------------------------------------------------
// NHRepNet fused forward, Round 14: 96-pt in-place tiles (nt=6) + 32-pt tail.
//
// Established (R1-R13):
//  - Occupancy tiers power-of-2 (64/128/256 regs); simple single-acc shapes
//    allocate cleanly to ~100 total regs (R9: 92); dual-acc interleave spills
//    at ~112 (R12); 64-tier caps at acc[2][2] (R10 spill). Gate: WRITE_SIZE.
//  - Cost per byte: LDS-B (~128 B/cyc/CU) is ~2x cheaper than L2-A (~56).
//    R13 (A up, B down, more barriers/pt) lost 20us vs R11 -> prefer cutting A.
//  - A/pt = 128KB/(nt*16); B/pt = 0.5KB*(256/C); MT*nt <= ~12 for regs.
//
// R14: C=32 (MT=2, 8 strip-waves), nt=6 -> 96-pt tiles, in-place act,
// 2 barriers/layer. A/pt = 1.33KB (L2-A ~27us), B/pt = 4KB (~54us LDS),
// acc[2][6] = 48 AGPR + ~55 arch ~= 103 <= 128-tier, 2 blocks/CU.
// Mixed grid: 871 x 96-pt + 512 x 32-pt tail blocks (drain latency).
// ---------------------------------------------------------------------------

using bf16x8 = __attribute__((ext_vector_type(8))) __bf16;
using f32x4  = __attribute__((ext_vector_type(4))) float;

#define LDA 264   // padded activation row stride (bf16)

#define OFFW0 0
#define OFFW1 8192
#define OFFW7 401408
#define WSB_BYTE_OFF 811008   // fp32 bias region
#define OFFB7 1792            // L0..L6 at l*256; L7 at 1792 (16 floats, padded)

#define SCALE_T2 144.26950408889634f      // 100*log2(e)
#define INV_SQRT2 0.70710678118654752f
#define LN2_100 0.0069314718055994531f    // ln2/100

__device__ __forceinline__ float fast_exp2(float x) {
#if __has_builtin(__builtin_amdgcn_exp2f)
    return __builtin_amdgcn_exp2f(x);
#else
    return exp2f(x);
#endif
}
__device__ __forceinline__ float fast_log2(float x) {
#if __has_builtin(__builtin_amdgcn_logf)
    return __builtin_amdgcn_logf(x);
#else
    return log2f(x);
#endif
}

// a2 = max(t2,0) + log2(1 + 2^-|t2|)   (t2-domain; scales folded into weights)
__device__ __forceinline__ float softplus_t2(float t2) {
    float e = fast_exp2(-fabsf(t2));
    float l = fast_log2(1.0f + e);
    return fmaxf(t2, 0.0f) + l;
}

__device__ __forceinline__ unsigned short bf16_rne(float f) {
    unsigned int u = __float_as_uint(f);
    unsigned int r = u + 0x7FFFu + ((u >> 16) & 1u);
    return (unsigned short)(r >> 16);
}

// One 256-out layer, in-place on act[NT*16][LDA]. 8 waves = 8 channel strips
// (wave owns ch [wave*32, wave*32+32)) covering all NT*16 points.
// MODE 1 = layer-3 splice (raw x into ch 253..255; W4 rows absorb scales).
template <int KK, int MODE, int NT>
__device__ __forceinline__ void layer_mm(
    const unsigned short* __restrict__ wfrag,
    const float* __restrict__ bias,
    unsigned short* act, const float* xst,
    int wave, int lane)
{
    const int quad = lane >> 4;
    const int l15  = lane & 15;

    f32x4 acc[2][NT];
#pragma unroll
    for (int i = 0; i < 2; ++i) {
        const int chb = (wave * 2 + i) * 16 + quad * 4;
        const float4 b4 = *(const float4*)(bias + chb);
#pragma unroll
        for (int nt = 0; nt < NT; ++nt)
            acc[i][nt] = f32x4{b4.x, b4.y, b4.z, b4.w};
    }

    const unsigned short* wbase = wfrag + (wave * 2 * KK * 64 + lane) * 8;

#pragma unroll
    for (int kk = 0; kk < KK; ++kk) {
        bf16x8 bfr[NT];
#pragma unroll
        for (int nt = 0; nt < NT; ++nt)
            bfr[nt] = *(const bf16x8*)(act + (nt * 16 + l15) * LDA + kk * 32 + quad * 8);
#pragma unroll
        for (int i = 0; i < 2; ++i) {
            bf16x8 afr = *(const bf16x8*)(wbase + (i * KK + kk) * 512);
#pragma unroll
            for (int nt = 0; nt < NT; ++nt)
                acc[i][nt] = __builtin_amdgcn_mfma_f32_16x16x32_bf16(afr, bfr[nt], acc[i][nt], 0, 0, 0);
        }
    }

    __syncthreads();   // all waves done READING act

#pragma unroll
    for (int i = 0; i < 2; ++i) {
        const int chb = (wave * 2 + i) * 16 + quad * 4;
#pragma unroll
        for (int nt = 0; nt < NT; ++nt) {
            const int pt = nt * 16 + l15;
            float vv[4];
#pragma unroll
            for (int r = 0; r < 4; ++r) {
                float s = softplus_t2(acc[i][nt][r]);
                if (MODE == 1) {
                    const int ch = chb + r;
                    if (ch >= 253)  // splice raw x (W4 rows absorb scales)
                        s = xst[pt * 4 + (ch - 253)];
                }
                vv[r] = s;
            }
            __hip_bfloat162 p01 = __float22bfloat162_rn(float2{vv[0], vv[1]});
            __hip_bfloat162 p23 = __float22bfloat162_rn(float2{vv[2], vv[3]});
            uint2 pk;
            pk.x = *(unsigned int*)&p01;
            pk.y = *(unsigned int*)&p23;
            *(uint2*)(act + pt * LDA + chb) = pk;
        }
    }

    __syncthreads();   // writes visible before next layer reads
}

// Full network for one tile of NT*16 points (NT=6 -> 96, NT=2 -> 32).
template <int NT>
__device__ __forceinline__ void run_net(
    const float* __restrict__ x, float* __restrict__ out,
    const unsigned short* __restrict__ wsW, const float* __restrict__ wsB,
    unsigned short* act, float* xst,
    int base_pt, int npts, int tid)
{
    const int wave = tid >> 6, lane = tid & 63;
    const int quad = lane >> 4, l15 = lane & 15;

    // stage x into act channels 0..2, zero-pad to 32 (K-pad for layer 0)
    for (int i = tid; i < NT * 16 * 32; i += 512) {
        const int pt = i >> 5, ch = i & 31;
        const int ptg = base_pt + pt;
        float v = 0.0f;
        if (ch < 3 && ptg < npts) v = x[ptg * 3 + ch];
        act[pt * LDA + ch] = bf16_rne(v);
        if (ch < 4) xst[pt * 4 + ch] = (ch < 3) ? v : 0.0f;
    }
    __syncthreads();

    layer_mm<1, 0, NT>(wsW + OFFW0, wsB + 0 * 256, act, xst, wave, lane);
    layer_mm<8, 0, NT>(wsW + OFFW1 + 0 * 65536, wsB + 1 * 256, act, xst, wave, lane);
    layer_mm<8, 0, NT>(wsW + OFFW1 + 1 * 65536, wsB + 2 * 256, act, xst, wave, lane);
    layer_mm<8, 1, NT>(wsW + OFFW1 + 2 * 65536, wsB + 3 * 256, act, xst, wave, lane);
    layer_mm<8, 0, NT>(wsW + OFFW1 + 3 * 65536, wsB + 4 * 256, act, xst, wave, lane);
    layer_mm<8, 0, NT>(wsW + OFFW1 + 4 * 65536, wsB + 5 * 256, act, xst, wave, lane);
    layer_mm<8, 0, NT>(wsW + OFFW1 + 5 * 65536, wsB + 6 * 256, act, xst, wave, lane);

    // layer 7: 256 -> 8 (W7 pre-scaled ln2/100, b7 raw). Waves 0..NT-1 handle
    // 16 pts each; act not written again -> no barrier.
    if (wave < NT) {
        const float4 b4 = *(const float4*)(wsB + OFFB7 + quad * 4);  // quads>=2: zeros
        f32x4 acc = f32x4{b4.x, b4.y, b4.z, b4.w};
        const unsigned short* w7 = wsW + OFFW7;
#pragma unroll
        for (int kk = 0; kk < 8; ++kk) {
            bf16x8 bfr = *(const bf16x8*)(act + (wave * 16 + l15) * LDA + kk * 32 + quad * 8);
            bf16x8 afr = *(const bf16x8*)(w7 + (kk * 64 + lane) * 8);
            acc = __builtin_amdgcn_mfma_f32_16x16x32_bf16(afr, bfr, acc, 0, 0, 0);
        }
        // quad0 lanes hold ch0-3, quad1 ch4-7 for pt = wave*16+l15
        float u0 = __shfl(acc[0], l15 + 16);
        float u1 = __shfl(acc[1], l15 + 16);
        float u2 = __shfl(acc[2], l15 + 16);
        float u3 = __shfl(acc[3], l15 + 16);
        if (quad == 0) {
            const int ptg = base_pt + wave * 16 + l15;
            if (ptg < npts) {
                const float v0 = acc[0], v1 = acc[1], v2 = acc[2], v3 = acc[3];
                const float v4 = u0, v5 = u1, v6 = u2, v7 = u3;
                const float m23   = fminf(v2, v3);
                const float m67   = fmaxf(v6, v7);
                const float m4567 = fminf(fminf(v4, v5), m67);
                const float h     = fmaxf(fmaxf(v0, v1), fmaxf(m23, m4567));
                float* o = out + (long)ptg * 9;
                o[0] = h;
                o[1] = v0; o[2] = v1; o[3] = v2; o[4] = v3;
                o[5] = v4; o[6] = v5; o[7] = v6; o[8] = v7;
            }
        }
    }
}

__global__ __launch_bounds__(512, 4)
void nhrep_main(const float* __restrict__ x, float* __restrict__ out,
                const unsigned short* __restrict__ wsW,
                const float* __restrict__ wsB, int npts, int nbig)
{
    __shared__ unsigned short act[96 * LDA];   // 50688 B
    __shared__ float xst[96 * 4];              // 1536 B -> 52224 B (2 blk/CU)
    const int b = blockIdx.x;
    if (b < nbig) {
        run_net<6>(x, out, wsW, wsB, act, xst, b * 96, npts, threadIdx.x);
    } else {
        run_net<2>(x, out, wsW, wsB, act, xst,
                   nbig * 96 + (b - nbig) * 32, npts, threadIdx.x);
    }
}

// ---------------------------------------------------------------------------
// Fused prepack with scale folding (proven since R4, identity k-mapping).
// Frag (mt,kk,lane,j) = scale(l,k) * W^T[mt*16+(lane&15)][kk*32+(lane>>4)*8+j]
// ---------------------------------------------------------------------------
struct PackArgs {
    const float* W[8];
    const float* b[8];
};

#define TOTAL_FRAGS 50688
#define TOTAL_BIAS  1808

__global__ void prepack_all(PackArgs args, unsigned short* __restrict__ dstW,
                            float* __restrict__ dstB)
{
    const int t = blockIdx.x * blockDim.x + threadIdx.x;
    const int FB[9]  = {0, 1024, 9216, 17408, 25600, 33792, 41984, 50176, 50688};
    const int KKs[8] = {1, 8, 8, 8, 8, 8, 8, 8};
    const int ind[8] = {3, 256, 256, 256, 256, 256, 256, 256};
    const int outd[8]= {256, 256, 256, 253, 256, 256, 256, 8};

    if (t < TOTAL_FRAGS) {
        int l = 0;
        while (t >= FB[l + 1]) ++l;
        const int f    = t - FB[l];
        const int lane = f & 63;
        const int kk   = (f >> 6) % KKs[l];
        const int mt   = f / (64 * KKs[l]);
        const int o    = mt * 16 + (lane & 15);
        const int kb   = kk * 32 + (lane >> 4) * 8;
        const float* W = args.W[l];
        const int in_d = ind[l], out_d = outd[l];

        unsigned short v[8];
#pragma unroll
        for (int j = 0; j < 8; ++j) {
            const int k = kb + j;
            float w = 0.0f;
            if (k < in_d && o < out_d) {
                float sc = 1.0f;
                if (l == 0) sc = SCALE_T2;
                else if (l == 4) sc = (k < 253) ? INV_SQRT2 : (SCALE_T2 * INV_SQRT2);
                else if (l == 7) sc = LN2_100;
                w = W[k * out_d + o] * sc;
            }
            unsigned int u = __float_as_uint(w);
            v[j] = (unsigned short)((u + 0x7FFFu + ((u >> 16) & 1u)) >> 16);
        }
        uint4 p;
        p.x = (unsigned int)v[0] | ((unsigned int)v[1] << 16);
        p.y = (unsigned int)v[2] | ((unsigned int)v[3] << 16);
        p.z = (unsigned int)v[4] | ((unsigned int)v[5] << 16);
        p.w = (unsigned int)v[6] | ((unsigned int)v[7] << 16);
        *(uint4*)(dstW + (long)t * 8) = p;
    } else if (t < TOTAL_FRAGS + TOTAL_BIAS) {
        const int u = t - TOTAL_FRAGS;
        const int l = (u < 1792) ? (u >> 8) : 7;
        const int idx = (l < 7) ? (u & 255) : (u - 1792);
        const float sc = (l < 7) ? SCALE_T2 : 1.0f;   // b7 stays in output units
        dstB[u] = (idx < outd[l]) ? args.b[l][idx] * sc : 0.0f;
    }
}

extern "C" void kernel_launch(void* const* d_in, const int* in_sizes, int n_in,
                              void* d_out, int out_size, void* d_ws, size_t ws_size,
                              hipStream_t stream)
{
    const float* x = (const float*)d_in[0];
    unsigned short* wsW = (unsigned short*)d_ws;
    float* wsB = (float*)((char*)d_ws + WSB_BYTE_OFF);

    PackArgs pa;
    for (int l = 0; l < 8; ++l) {
        pa.W[l] = (const float*)d_in[1 + 2 * l];
        pa.b[l] = (const float*)d_in[2 + 2 * l];
    }
    const int ptot = TOTAL_FRAGS + TOTAL_BIAS;
    prepack_all<<<(ptot + 255) / 256, 256, 0, stream>>>(pa, wsW, wsB);

    const int npts = in_sizes[0] / 3;            // 100000
    // Mixed grid: 96-pt blocks for the bulk, 32-pt blocks for the drain tail.
    int nbig, nsmall;
    const int tail_pts = 16384;
    if (npts > tail_pts) {
        nbig = (npts - tail_pts + 95) / 96;      // 871
        const int base_small = nbig * 96;
        nsmall = (npts - base_small + 31) / 32;  // ~512
    } else {
        nbig = 0;
        nsmall = (npts + 31) / 32;
    }
    nhrep_main<<<nbig + nsmall, 512, 0, stream>>>(x, (float*)d_out, wsW, wsB,
                                                  npts, nbig);
}